// Round 7
// baseline (295.082 us; speedup 1.0000x reference)
//
#include <hip/hip_runtime.h>

// RelationGAT, collapsed + fused. ROUND 7 = PHASE-ABLATION ATTRIBUTION.
//   M1 <0,0>: stream+softmax only (const p4), nbar -> ws scratch
//   M2 <1,0>: + real phase-1 P=x@A,          nbar -> ws scratch
//   M3 <1,1>: full (== R6 kernel),           out  -> d_out (validated)
// stream = F_M1; phase1 = F_M2-F_M1; phase3 = F_M3-F_M2;
// F_M1+F_M2 = dur_R7 - 118.7 - launch_delta(~4us).

#define NB 16384
#define NNBR 50
#define DIM 128
#define ROWS_W 8  // batch rows per wave

// ---------------- cross-lane add helpers -------------------------------------
template <int CTRL>
__device__ __forceinline__ float dpp_add(float x) {
  int v = __builtin_amdgcn_update_dpp(0, __builtin_bit_cast(int, x), CTRL,
                                      0xF, 0xF, true);
  return x + __builtin_bit_cast(float, v);
}

__device__ __forceinline__ float half_sum(float x) {
  x = dpp_add<0xB1>(x);   // xor 1
  x = dpp_add<0x4E>(x);   // xor 2
  x = dpp_add<0x141>(x);  // row_half_mirror
  x = dpp_add<0x140>(x);  // row_mirror
  x += __shfl_xor(x, 16, 64);
  return x;
}

// ---------------- K1: A and MT, LDS-staged (unchanged) -----------------------
__global__ __launch_bounds__(256) void precompute_weights(
    const float* __restrict__ Wq, const float* __restrict__ Wk,
    const float* __restrict__ Wv, float* __restrict__ A,
    float* __restrict__ MT) {
  __shared__ float wk[128 * 128];   // 64 KB
  __shared__ float wrow[8 * 128];   // 4 KB
  int t = threadIdx.x;
  int g = blockIdx.x;
  bool isA = g < 16;
  int r0 = (g & 15) * 8;

  const float4* wk4 = (const float4*)Wk;
  float4* wkl4 = (float4*)wk;
  #pragma unroll
  for (int i = 0; i < 16; ++i) wkl4[t + i * 256] = wk4[t + i * 256];

  if (isA) {
    #pragma unroll
    for (int i = 0; i < 4; ++i) {            // wrow[q][o] = Wq[o][r0+q]
      int idx = t + i * 256;
      int q = idx >> 7, o = idx & 127;
      wrow[q * 128 + o] = Wq[o * 128 + r0 + q];
    }
  } else {
    const float4* wv4 = (const float4*)(Wv + r0 * 128);
    float4* wr4 = (float4*)wrow;             // wrow[q][o] = Wv[r0+q][o]
    if (t < 256) wr4[t] = wv4[t];
  }
  __syncthreads();

  int d = t & 127;
  int h = (t >> 7) * 4;
  float acc[4] = {0.f, 0.f, 0.f, 0.f};
  #pragma unroll 8
  for (int o = 0; o < 128; ++o) {
    float b = wk[o * 128 + d];
    #pragma unroll
    for (int qq = 0; qq < 4; ++qq)
      acc[qq] += wrow[(h + qq) * 128 + o] * b;
  }
  if (isA) {
    #pragma unroll
    for (int qq = 0; qq < 4; ++qq) A[(r0 + h + qq) * 128 + d] = acc[qq];
  } else {
    #pragma unroll
    for (int qq = 0; qq < 4; ++qq) MT[d * 128 + r0 + h + qq] = acc[qq];
  }
}

// ---------------- K2: fused kernel, phase-ablation template ------------------
template <int DO_P1, int DO_P3>
__global__ __launch_bounds__(256, 2) void fused_attn(
    const float* __restrict__ x, const float* __restrict__ A,
    const float* __restrict__ MT, const float* __restrict__ nbr,
    float* __restrict__ outbuf) {
  __shared__ float nbar_s[4 * ROWS_W][128];  // 16 KB, strictly per-wave rows
  int wave = threadIdx.x >> 6;
  int lane = threadIdx.x & 63;
  int b0 = (blockIdx.x * 4 + wave) * ROWS_W;
  int c = lane & 31;

  float4 p4[ROWS_W];
  if constexpr (DO_P1) {
    // ---- phase 1: p2[r] = (x@A)[b0+r][2l..2l+1], then shfl to half-dup float4
    float2 p2[ROWS_W];
    #pragma unroll
    for (int r = 0; r < ROWS_W; ++r) p2[r] = make_float2(0.f, 0.f);

    for (int j = 0; j < 128; j += 4) {
      float4 xv[ROWS_W];
      #pragma unroll
      for (int r = 0; r < ROWS_W; ++r)
        xv[r] = *(const float4*)(x + (size_t)(b0 + r) * DIM + j);
      #pragma unroll
      for (int jj = 0; jj < 4; ++jj) {
        float2 a = ((const float2*)(A + (j + jj) * 128))[lane];
        #pragma unroll
        for (int r = 0; r < ROWS_W; ++r) {
          float xs = (jj == 0) ? xv[r].x : (jj == 1) ? xv[r].y
                   : (jj == 2) ? xv[r].z : xv[r].w;
          p2[r].x += xs * a.x;
          p2[r].y += xs * a.y;
        }
      }
    }
    #pragma unroll
    for (int r = 0; r < ROWS_W; ++r) {
      p4[r].x = __shfl(p2[r].x, 2 * c, 64);
      p4[r].y = __shfl(p2[r].y, 2 * c, 64);
      p4[r].z = __shfl(p2[r].x, 2 * c + 1, 64);
      p4[r].w = __shfl(p2[r].y, 2 * c + 1, 64);
    }
  } else {
    // ablation: fixed p4 (keeps all downstream work live & data-dependent)
    #pragma unroll
    for (int r = 0; r < ROWS_W; ++r)
      p4[r] = make_float4(0.5f, -0.25f, 0.125f, 1.0f);
  }

  // ---- phase 2: stream neighbors, online softmax (pair trick per row)
  const float4* nr0 = (const float4*)(nbr + (size_t)b0 * NNBR * DIM);
  float m[ROWS_W], l[ROWS_W];
  float4 acc[ROWS_W], v[ROWS_W], vn[ROWS_W];
  #pragma unroll
  for (int r = 0; r < ROWS_W; ++r) {
    m[r] = -INFINITY;
    l[r] = 0.f;
    acc[r] = make_float4(0.f, 0.f, 0.f, 0.f);
    v[r] = nr0[(size_t)r * (NNBR * 32) + lane];  // pair 0 of row r
  }

  for (int np = 0; np < 25; ++np) {
    int nxt = (np + 1 < 25) ? (np + 1) : np;
    #pragma unroll
    for (int r = 0; r < ROWS_W; ++r)
      vn[r] = nr0[(size_t)r * (NNBR * 32) + nxt * 64 + lane];

    #pragma unroll
    for (int r = 0; r < ROWS_W; ++r) {
      float partial = p4[r].x * v[r].x + p4[r].y * v[r].y +
                      p4[r].z * v[r].z + p4[r].w * v[r].w;
      float s = half_sum(partial);
      float so = __shfl_xor(s, 32, 64);
      float mn = fmaxf(m[r], fmaxf(s, so));
      float scale = __expf(m[r] - mn);
      float e = __expf(s - mn);
      l[r] = l[r] * scale + e;
      acc[r].x = acc[r].x * scale + e * v[r].x;
      acc[r].y = acc[r].y * scale + e * v[r].y;
      acc[r].z = acc[r].z * scale + e * v[r].z;
      acc[r].w = acc[r].w * scale + e * v[r].w;
      m[r] = mn;
      v[r] = vn[r];
    }
  }

  #pragma unroll
  for (int r = 0; r < ROWS_W; ++r) {
    l[r] += __shfl_xor(l[r], 32, 64);
    acc[r].x += __shfl_xor(acc[r].x, 32, 64);
    acc[r].y += __shfl_xor(acc[r].y, 32, 64);
    acc[r].z += __shfl_xor(acc[r].z, 32, 64);
    acc[r].w += __shfl_xor(acc[r].w, 32, 64);
  }

  if constexpr (!DO_P3) {
    // ablation: write normalized nbar straight to outbuf (coalesced 512B/row)
    if (lane < 32) {
      #pragma unroll
      for (int r = 0; r < ROWS_W; ++r) {
        float inv = 1.f / l[r];
        float4 o4 = make_float4(acc[r].x * inv, acc[r].y * inv,
                                acc[r].z * inv, acc[r].w * inv);
        *(float4*)(outbuf + (size_t)(b0 + r) * DIM + c * 4) = o4;
      }
    }
    return;
  } else {
    if (lane < 32) {
      #pragma unroll
      for (int r = 0; r < ROWS_W; ++r) {
        float inv = 1.f / l[r];
        float4 o4 = make_float4(acc[r].x * inv, acc[r].y * inv,
                                acc[r].z * inv, acc[r].w * inv);
        *(float4*)&nbar_s[wave * ROWS_W + r][c * 4] = o4;
      }
    }

    // ---- phase 3: out[b][t] = sum_d nbar[d]*MT[d][t]; lane owns t={2l,2l+1}
    float2 o[ROWS_W];
    #pragma unroll
    for (int r = 0; r < ROWS_W; ++r) o[r] = make_float2(0.f, 0.f);

    for (int d = 0; d < 128; d += 4) {
      float4 nb[ROWS_W];
      #pragma unroll
      for (int r = 0; r < ROWS_W; ++r)
        nb[r] = *(const float4*)&nbar_s[wave * ROWS_W + r][d];
      #pragma unroll
      for (int dd = 0; dd < 4; ++dd) {
        float2 mt = ((const float2*)(MT + (d + dd) * 128))[lane];
        #pragma unroll
        for (int r = 0; r < ROWS_W; ++r) {
          float nv = (dd == 0) ? nb[r].x : (dd == 1) ? nb[r].y
                   : (dd == 2) ? nb[r].z : nb[r].w;
          o[r].x += nv * mt.x;
          o[r].y += nv * mt.y;
        }
      }
    }
    #pragma unroll
    for (int r = 0; r < ROWS_W; ++r)
      ((float2*)(outbuf + (size_t)(b0 + r) * DIM))[lane] = o[r];
  }
}

// ---------------- launcher ---------------------------------------------------
extern "C" void kernel_launch(void* const* d_in, const int* in_sizes, int n_in,
                              void* d_out, int out_size, void* d_ws,
                              size_t ws_size, hipStream_t stream) {
  const float* x   = (const float*)d_in[0];
  const float* nbr = (const float*)d_in[1];
  const float* Wq  = (const float*)d_in[2];
  const float* Wk  = (const float*)d_in[3];
  const float* Wv  = (const float*)d_in[4];
  float* out = (float*)d_out;

  char* ws = (char*)d_ws;
  float* A    = (float*)(ws);                      // 64 KB
  float* MT   = (float*)(ws + 65536);              // 64 KB
  float* scr1 = (float*)(ws + (1 << 20));          // 8 MB scratch
  float* scr2 = (float*)(ws + (1 << 20) + (8 << 20));  // 8 MB scratch

  precompute_weights<<<32, 256, 0, stream>>>(Wq, Wk, Wv, A, MT);
  fused_attn<0, 0><<<NB / (4 * ROWS_W), 256, 0, stream>>>(x, A, MT, nbr, scr1);
  fused_attn<1, 0><<<NB / (4 * ROWS_W), 256, 0, stream>>>(x, A, MT, nbr, scr2);
  fused_attn<1, 1><<<NB / (4 * ROWS_W), 256, 0, stream>>>(x, A, MT, nbr, out);
}

// Round 8
// 124.082 us; speedup vs baseline: 2.3781x; 2.3781x over previous
//
#include <hip/hip_runtime.h>

// RelationGAT, collapsed + fused, R8: LDS-staged A/MT to kill L2-latency
// exposure in the projection phases (R7 ablation: stream 80us, p1 13, p3 17).
//   K1: A = Wq^T@Wk (A[j][d]), MT[d][t] = (Wv@Wk)[t][d]
//   K2 per wave = 8 batch rows:
//     phase0: block stages A (64KB) -> LDS
//     phase1: p = x@A from LDS
//     phase2: stream neighbor (HBM-bound), online softmax;
//             MT staged LDS-ward under the stream (16 float4 pieces/thread)
//     phase3: out = nbar@MT from LDS

#define NB 16384
#define NNBR 50
#define DIM 128
#define ROWS_W 8  // batch rows per wave

// ---------------- cross-lane add helpers -------------------------------------
template <int CTRL>
__device__ __forceinline__ float dpp_add(float x) {
  int v = __builtin_amdgcn_update_dpp(0, __builtin_bit_cast(int, x), CTRL,
                                      0xF, 0xF, true);
  return x + __builtin_bit_cast(float, v);
}

__device__ __forceinline__ float half_sum(float x) {
  x = dpp_add<0xB1>(x);   // xor 1
  x = dpp_add<0x4E>(x);   // xor 2
  x = dpp_add<0x141>(x);  // row_half_mirror
  x = dpp_add<0x140>(x);  // row_mirror
  x += __shfl_xor(x, 16, 64);
  return x;
}

// ---------------- K1: A and MT, LDS-staged (unchanged) -----------------------
__global__ __launch_bounds__(256) void precompute_weights(
    const float* __restrict__ Wq, const float* __restrict__ Wk,
    const float* __restrict__ Wv, float* __restrict__ A,
    float* __restrict__ MT) {
  __shared__ float wk[128 * 128];   // 64 KB
  __shared__ float wrow[8 * 128];   // 4 KB
  int t = threadIdx.x;
  int g = blockIdx.x;
  bool isA = g < 16;
  int r0 = (g & 15) * 8;

  const float4* wk4 = (const float4*)Wk;
  float4* wkl4 = (float4*)wk;
  #pragma unroll
  for (int i = 0; i < 16; ++i) wkl4[t + i * 256] = wk4[t + i * 256];

  if (isA) {
    #pragma unroll
    for (int i = 0; i < 4; ++i) {            // wrow[q][o] = Wq[o][r0+q]
      int idx = t + i * 256;
      int q = idx >> 7, o = idx & 127;
      wrow[q * 128 + o] = Wq[o * 128 + r0 + q];
    }
  } else {
    const float4* wv4 = (const float4*)(Wv + r0 * 128);
    float4* wr4 = (float4*)wrow;             // wrow[q][o] = Wv[r0+q][o]
    if (t < 256) wr4[t] = wv4[t];
  }
  __syncthreads();

  int d = t & 127;
  int h = (t >> 7) * 4;
  float acc[4] = {0.f, 0.f, 0.f, 0.f};
  #pragma unroll 8
  for (int o = 0; o < 128; ++o) {
    float b = wk[o * 128 + d];
    #pragma unroll
    for (int qq = 0; qq < 4; ++qq)
      acc[qq] += wrow[(h + qq) * 128 + o] * b;
  }
  if (isA) {
    #pragma unroll
    for (int qq = 0; qq < 4; ++qq) A[(r0 + h + qq) * 128 + d] = acc[qq];
  } else {
    #pragma unroll
    for (int qq = 0; qq < 4; ++qq) MT[d * 128 + r0 + h + qq] = acc[qq];
  }
}

// ---------------- K2: fused, LDS-staged projections --------------------------
// 4 waves/block, 8 rows/wave -> 32 rows/block, grid = 512, 2 blocks/CU (80KB).
__global__ __launch_bounds__(256, 2) void fused_attn(
    const float* __restrict__ x, const float* __restrict__ A,
    const float* __restrict__ MT, const float* __restrict__ nbr,
    float* __restrict__ out) {
  __shared__ float ldsA[128 * 128];          // 64 KB: holds A, then MT
  __shared__ float nbar_s[4 * ROWS_W][128];  // 16 KB
  int tid = threadIdx.x;
  int wave = tid >> 6;
  int lane = tid & 63;
  int b0 = (blockIdx.x * 4 + wave) * ROWS_W;
  int c = lane & 31;

  // ---- phase 0: stage A into LDS (bulk coalesced, 16-deep MLP)
  {
    const float4* A4 = (const float4*)A;
    float4* L4 = (float4*)ldsA;
    #pragma unroll
    for (int i = 0; i < 16; ++i) L4[tid + i * 256] = A4[tid + i * 256];
  }
  __syncthreads();

  // ---- phase 1: p2[r] = (x@A)[b0+r][2l..2l+1], A from LDS
  float2 p2[ROWS_W];
  #pragma unroll
  for (int r = 0; r < ROWS_W; ++r) p2[r] = make_float2(0.f, 0.f);

  for (int j = 0; j < 128; j += 4) {
    float4 xv[ROWS_W];
    #pragma unroll
    for (int r = 0; r < ROWS_W; ++r)
      xv[r] = *(const float4*)(x + (size_t)(b0 + r) * DIM + j);  // wave-uniform
    #pragma unroll
    for (int jj = 0; jj < 4; ++jj) {
      float2 a = ((const float2*)(ldsA + (j + jj) * 128))[lane];  // ds_read_b64
      #pragma unroll
      for (int r = 0; r < ROWS_W; ++r) {
        float xs = (jj == 0) ? xv[r].x : (jj == 1) ? xv[r].y
                 : (jj == 2) ? xv[r].z : xv[r].w;
        p2[r].x += xs * a.x;
        p2[r].y += xs * a.y;
      }
    }
  }

  // rearrange to half-duplicated float4: lane (both halves) owns cols 4c..4c+3
  float4 p4[ROWS_W];
  #pragma unroll
  for (int r = 0; r < ROWS_W; ++r) {
    p4[r].x = __shfl(p2[r].x, 2 * c, 64);
    p4[r].y = __shfl(p2[r].y, 2 * c, 64);
    p4[r].z = __shfl(p2[r].x, 2 * c + 1, 64);
    p4[r].w = __shfl(p2[r].y, 2 * c + 1, 64);
  }
  __syncthreads();  // all waves done reading ldsA; safe to overwrite with MT

  // ---- phase 2: stream neighbors, online softmax; stage MT under the stream
  const float4* nr0 = (const float4*)(nbr + (size_t)b0 * NNBR * DIM);
  const float4* MT4 = (const float4*)MT;
  float4* mtl4 = (float4*)ldsA;
  float4 mtreg = MT4[tid];  // piece 0

  float m[ROWS_W], l[ROWS_W];
  float4 acc[ROWS_W], v[ROWS_W], vn[ROWS_W];
  #pragma unroll
  for (int r = 0; r < ROWS_W; ++r) {
    m[r] = -INFINITY;
    l[r] = 0.f;
    acc[r] = make_float4(0.f, 0.f, 0.f, 0.f);
    v[r] = nr0[(size_t)r * (NNBR * 32) + lane];  // pair 0 of row r
  }

  for (int np = 0; np < 25; ++np) {
    // MT staging: ds_write piece np (loaded last iter), load piece np+1.
    // The vmcnt wait for mtreg hides under this iteration's stream loads.
    if (np < 16) {
      mtl4[tid + np * 256] = mtreg;
      if (np < 15) mtreg = MT4[tid + (np + 1) * 256];
    }

    int nxt = (np + 1 < 25) ? (np + 1) : np;
    #pragma unroll
    for (int r = 0; r < ROWS_W; ++r)
      vn[r] = nr0[(size_t)r * (NNBR * 32) + nxt * 64 + lane];

    #pragma unroll
    for (int r = 0; r < ROWS_W; ++r) {
      float partial = p4[r].x * v[r].x + p4[r].y * v[r].y +
                      p4[r].z * v[r].z + p4[r].w * v[r].w;
      float s = half_sum(partial);
      float so = __shfl_xor(s, 32, 64);
      float mn = fmaxf(m[r], fmaxf(s, so));
      float scale = __expf(m[r] - mn);
      float e = __expf(s - mn);
      l[r] = l[r] * scale + e;
      acc[r].x = acc[r].x * scale + e * v[r].x;
      acc[r].y = acc[r].y * scale + e * v[r].y;
      acc[r].z = acc[r].z * scale + e * v[r].z;
      acc[r].w = acc[r].w * scale + e * v[r].w;
      m[r] = mn;
      v[r] = vn[r];
    }
  }

  // merge half-wave accumulators; stash normalized nbar in per-wave LDS rows
  #pragma unroll
  for (int r = 0; r < ROWS_W; ++r) {
    l[r] += __shfl_xor(l[r], 32, 64);
    acc[r].x += __shfl_xor(acc[r].x, 32, 64);
    acc[r].y += __shfl_xor(acc[r].y, 32, 64);
    acc[r].z += __shfl_xor(acc[r].z, 32, 64);
    acc[r].w += __shfl_xor(acc[r].w, 32, 64);
  }
  if (lane < 32) {
    #pragma unroll
    for (int r = 0; r < ROWS_W; ++r) {
      float inv = 1.f / l[r];
      float4 o4 = make_float4(acc[r].x * inv, acc[r].y * inv,
                              acc[r].z * inv, acc[r].w * inv);
      *(float4*)&nbar_s[wave * ROWS_W + r][c * 4] = o4;
    }
  }
  __syncthreads();  // MT staging (block-shared) + nbar writes all visible

  // ---- phase 3: out[b][t] = sum_d nbar[d]*MT[d][t], MT from LDS
  float2 o[ROWS_W];
  #pragma unroll
  for (int r = 0; r < ROWS_W; ++r) o[r] = make_float2(0.f, 0.f);

  for (int d = 0; d < 128; d += 4) {
    float4 nb[ROWS_W];
    #pragma unroll
    for (int r = 0; r < ROWS_W; ++r)
      nb[r] = *(const float4*)&nbar_s[wave * ROWS_W + r][d];  // LDS broadcast
    #pragma unroll
    for (int dd = 0; dd < 4; ++dd) {
      float2 mt = ((const float2*)(ldsA + (d + dd) * 128))[lane];  // ds_read_b64
      #pragma unroll
      for (int r = 0; r < ROWS_W; ++r) {
        float nv = (dd == 0) ? nb[r].x : (dd == 1) ? nb[r].y
                 : (dd == 2) ? nb[r].z : nb[r].w;
        o[r].x += nv * mt.x;
        o[r].y += nv * mt.y;
      }
    }
  }
  #pragma unroll
  for (int r = 0; r < ROWS_W; ++r)
    ((float2*)(out + (size_t)(b0 + r) * DIM))[lane] = o[r];
}

// ---------------- launcher ---------------------------------------------------
extern "C" void kernel_launch(void* const* d_in, const int* in_sizes, int n_in,
                              void* d_out, int out_size, void* d_ws,
                              size_t ws_size, hipStream_t stream) {
  const float* x   = (const float*)d_in[0];
  const float* nbr = (const float*)d_in[1];
  const float* Wq  = (const float*)d_in[2];
  const float* Wk  = (const float*)d_in[3];
  const float* Wv  = (const float*)d_in[4];
  float* out = (float*)d_out;

  char* ws = (char*)d_ws;
  float* A  = (float*)(ws);            // 64 KB
  float* MT = (float*)(ws + 65536);    // 64 KB

  precompute_weights<<<32, 256, 0, stream>>>(Wq, Wk, Wv, A, MT);
  fused_attn<<<NB / (4 * ROWS_W), 256, 0, stream>>>(x, A, MT, nbr, out);
}

// Round 9
// 100.603 us; speedup vs baseline: 2.9331x; 1.2334x over previous
//
#include <hip/hip_runtime.h>

// RelationGAT, collapsed + fused, R9:
//   - x rows staged per-wave into LDS at entry (kills the 32-deep HBM-latency
//     chain that was phase-1's 13us; R7 ablation + cycle arithmetic)
//   - A staged to LDS per block (R8's phase 0, kept)
//   - stream loop pristine (R6 form; R8's in-stream MT staging removed)
//   - phase 3 reads MT from L2 with unroll-4 for MLP
//   K1: A = Wq^T@Wk (A[j][d]), MT[d][t] = (Wv@Wk)[t][d]

#define NB 16384
#define NNBR 50
#define DIM 128
#define ROWS_W 8  // batch rows per wave

// ---------------- cross-lane add helpers -------------------------------------
template <int CTRL>
__device__ __forceinline__ float dpp_add(float x) {
  int v = __builtin_amdgcn_update_dpp(0, __builtin_bit_cast(int, x), CTRL,
                                      0xF, 0xF, true);
  return x + __builtin_bit_cast(float, v);
}

__device__ __forceinline__ float half_sum(float x) {
  x = dpp_add<0xB1>(x);   // xor 1
  x = dpp_add<0x4E>(x);   // xor 2
  x = dpp_add<0x141>(x);  // row_half_mirror
  x = dpp_add<0x140>(x);  // row_mirror
  x += __shfl_xor(x, 16, 64);
  return x;
}

// ---------------- K1: A and MT, LDS-staged (unchanged) -----------------------
__global__ __launch_bounds__(256) void precompute_weights(
    const float* __restrict__ Wq, const float* __restrict__ Wk,
    const float* __restrict__ Wv, float* __restrict__ A,
    float* __restrict__ MT) {
  __shared__ float wk[128 * 128];   // 64 KB
  __shared__ float wrow[8 * 128];   // 4 KB
  int t = threadIdx.x;
  int g = blockIdx.x;
  bool isA = g < 16;
  int r0 = (g & 15) * 8;

  const float4* wk4 = (const float4*)Wk;
  float4* wkl4 = (float4*)wk;
  #pragma unroll
  for (int i = 0; i < 16; ++i) wkl4[t + i * 256] = wk4[t + i * 256];

  if (isA) {
    #pragma unroll
    for (int i = 0; i < 4; ++i) {            // wrow[q][o] = Wq[o][r0+q]
      int idx = t + i * 256;
      int q = idx >> 7, o = idx & 127;
      wrow[q * 128 + o] = Wq[o * 128 + r0 + q];
    }
  } else {
    const float4* wv4 = (const float4*)(Wv + r0 * 128);
    float4* wr4 = (float4*)wrow;             // wrow[q][o] = Wv[r0+q][o]
    if (t < 256) wr4[t] = wv4[t];
  }
  __syncthreads();

  int d = t & 127;
  int h = (t >> 7) * 4;
  float acc[4] = {0.f, 0.f, 0.f, 0.f};
  #pragma unroll 8
  for (int o = 0; o < 128; ++o) {
    float b = wk[o * 128 + d];
    #pragma unroll
    for (int qq = 0; qq < 4; ++qq)
      acc[qq] += wrow[(h + qq) * 128 + o] * b;
  }
  if (isA) {
    #pragma unroll
    for (int qq = 0; qq < 4; ++qq) A[(r0 + h + qq) * 128 + d] = acc[qq];
  } else {
    #pragma unroll
    for (int qq = 0; qq < 4; ++qq) MT[d * 128 + r0 + h + qq] = acc[qq];
  }
}

// ---------------- K2: fused -------------------------------------------------
// 4 waves/block, 8 rows/wave -> 32 rows/block, grid = 512, 2 blocks/CU (80KB).
__global__ __launch_bounds__(256, 2) void fused_attn(
    const float* __restrict__ x, const float* __restrict__ A,
    const float* __restrict__ MT, const float* __restrict__ nbr,
    float* __restrict__ out) {
  __shared__ float ldsA[128 * 128];          // 64 KB: A (phase 1), permanent
  __shared__ float nbar_s[4 * ROWS_W][128];  // 16 KB: x rows, later nbar
  int tid = threadIdx.x;
  int wave = tid >> 6;
  int lane = tid & 63;
  int b0 = (blockIdx.x * 4 + wave) * ROWS_W;
  int c = lane & 31;

  // ---- phase 0a: stage this wave's 8 x-rows into its own nbar_s region
  // (4 KB coalesced, 4 loads all in flight -> one HBM latency, not 32)
  {
    const float4* xg = (const float4*)(x + (size_t)b0 * DIM);
    float4* xl = (float4*)&nbar_s[wave * ROWS_W][0];
    #pragma unroll
    for (int i = 0; i < 4; ++i) xl[i * 64 + lane] = xg[i * 64 + lane];
  }
  // ---- phase 0b: stage A into LDS (block-wide, 16-deep MLP)
  {
    const float4* A4 = (const float4*)A;
    float4* L4 = (float4*)ldsA;
    #pragma unroll
    for (int i = 0; i < 16; ++i) L4[tid + i * 256] = A4[tid + i * 256];
  }
  __syncthreads();  // A visible to block (x is wave-private, covered anyway)

  // ---- phase 1: p2[r] = (x@A)[b0+r][2l..2l+1], x and A from LDS
  float2 p2[ROWS_W];
  #pragma unroll
  for (int r = 0; r < ROWS_W; ++r) p2[r] = make_float2(0.f, 0.f);

  #pragma unroll 2
  for (int j = 0; j < 128; j += 4) {
    float4 xv[ROWS_W];
    #pragma unroll
    for (int r = 0; r < ROWS_W; ++r)
      xv[r] = *(const float4*)&nbar_s[wave * ROWS_W + r][j];  // uniform bcast
    #pragma unroll
    for (int jj = 0; jj < 4; ++jj) {
      float2 a = ((const float2*)(ldsA + (j + jj) * 128))[lane];  // 2-way: free
      #pragma unroll
      for (int r = 0; r < ROWS_W; ++r) {
        float xs = (jj == 0) ? xv[r].x : (jj == 1) ? xv[r].y
                 : (jj == 2) ? xv[r].z : xv[r].w;
        p2[r].x += xs * a.x;
        p2[r].y += xs * a.y;
      }
    }
  }

  // rearrange to half-duplicated float4: lane (both halves) owns cols 4c..4c+3
  float4 p4[ROWS_W];
  #pragma unroll
  for (int r = 0; r < ROWS_W; ++r) {
    p4[r].x = __shfl(p2[r].x, 2 * c, 64);
    p4[r].y = __shfl(p2[r].y, 2 * c, 64);
    p4[r].z = __shfl(p2[r].x, 2 * c + 1, 64);
    p4[r].w = __shfl(p2[r].y, 2 * c + 1, 64);
  }

  // ---- phase 2: stream neighbors, online softmax (pristine R6 loop)
  const float4* nr0 = (const float4*)(nbr + (size_t)b0 * NNBR * DIM);
  float m[ROWS_W], l[ROWS_W];
  float4 acc[ROWS_W], v[ROWS_W], vn[ROWS_W];
  #pragma unroll
  for (int r = 0; r < ROWS_W; ++r) {
    m[r] = -INFINITY;
    l[r] = 0.f;
    acc[r] = make_float4(0.f, 0.f, 0.f, 0.f);
    v[r] = nr0[(size_t)r * (NNBR * 32) + lane];  // pair 0 of row r
  }

  for (int np = 0; np < 25; ++np) {
    int nxt = (np + 1 < 25) ? (np + 1) : np;     // clamp: last re-reads
    #pragma unroll
    for (int r = 0; r < ROWS_W; ++r)
      vn[r] = nr0[(size_t)r * (NNBR * 32) + nxt * 64 + lane];

    #pragma unroll
    for (int r = 0; r < ROWS_W; ++r) {
      float partial = p4[r].x * v[r].x + p4[r].y * v[r].y +
                      p4[r].z * v[r].z + p4[r].w * v[r].w;
      float s = half_sum(partial);
      float so = __shfl_xor(s, 32, 64);
      float mn = fmaxf(m[r], fmaxf(s, so));
      float scale = __expf(m[r] - mn);
      float e = __expf(s - mn);
      l[r] = l[r] * scale + e;
      acc[r].x = acc[r].x * scale + e * v[r].x;
      acc[r].y = acc[r].y * scale + e * v[r].y;
      acc[r].z = acc[r].z * scale + e * v[r].z;
      acc[r].w = acc[r].w * scale + e * v[r].w;
      m[r] = mn;
      v[r] = vn[r];
    }
  }

  // merge half-wave accumulators; overwrite this wave's x region with nbar
  // (in-wave ordering: phase-1 x reads long done; no barrier needed)
  #pragma unroll
  for (int r = 0; r < ROWS_W; ++r) {
    l[r] += __shfl_xor(l[r], 32, 64);
    acc[r].x += __shfl_xor(acc[r].x, 32, 64);
    acc[r].y += __shfl_xor(acc[r].y, 32, 64);
    acc[r].z += __shfl_xor(acc[r].z, 32, 64);
    acc[r].w += __shfl_xor(acc[r].w, 32, 64);
  }
  if (lane < 32) {
    #pragma unroll
    for (int r = 0; r < ROWS_W; ++r) {
      float inv = 1.f / l[r];
      float4 o4 = make_float4(acc[r].x * inv, acc[r].y * inv,
                              acc[r].z * inv, acc[r].w * inv);
      *(float4*)&nbar_s[wave * ROWS_W + r][c * 4] = o4;
    }
  }

  // ---- phase 3: out[b][t] = sum_d nbar[d]*MT[d][t]; MT via L2, unroll-4 MLP
  float2 o[ROWS_W];
  #pragma unroll
  for (int r = 0; r < ROWS_W; ++r) o[r] = make_float2(0.f, 0.f);

  #pragma unroll 4
  for (int d = 0; d < 128; d += 4) {
    float4 nb[ROWS_W];
    #pragma unroll
    for (int r = 0; r < ROWS_W; ++r)
      nb[r] = *(const float4*)&nbar_s[wave * ROWS_W + r][d];  // LDS broadcast
    #pragma unroll
    for (int dd = 0; dd < 4; ++dd) {
      float2 mt = ((const float2*)(MT + (d + dd) * 128))[lane];  // 512B coalesced
      #pragma unroll
      for (int r = 0; r < ROWS_W; ++r) {
        float nv = (dd == 0) ? nb[r].x : (dd == 1) ? nb[r].y
                 : (dd == 2) ? nb[r].z : nb[r].w;
        o[r].x += nv * mt.x;
        o[r].y += nv * mt.y;
      }
    }
  }
  #pragma unroll
  for (int r = 0; r < ROWS_W; ++r)
    ((float2*)(out + (size_t)(b0 + r) * DIM))[lane] = o[r];
}

// ---------------- launcher ---------------------------------------------------
extern "C" void kernel_launch(void* const* d_in, const int* in_sizes, int n_in,
                              void* d_out, int out_size, void* d_ws,
                              size_t ws_size, hipStream_t stream) {
  const float* x   = (const float*)d_in[0];
  const float* nbr = (const float*)d_in[1];
  const float* Wq  = (const float*)d_in[2];
  const float* Wk  = (const float*)d_in[3];
  const float* Wv  = (const float*)d_in[4];
  float* out = (float*)d_out;

  char* ws = (char*)d_ws;
  float* A  = (float*)(ws);            // 64 KB
  float* MT = (float*)(ws + 65536);    // 64 KB

  precompute_weights<<<32, 256, 0, stream>>>(Wq, Wk, Wv, A, MT);
  fused_attn<<<NB / (4 * ROWS_W), 256, 0, stream>>>(x, A, MT, nbr, out);
}

// Round 10
// 97.943 us; speedup vs baseline: 3.0128x; 1.0272x over previous
//
#include <hip/hip_runtime.h>

// RelationGAT, collapsed + fused, R10:
//   - stream's first 2 neighbor-pairs issued at kernel entry (HBM busy during
//     the phase-0/1 prologue, which previously idled memory chip-wide)
//   - 2-deep prefetch in the stream loop (16KB/wave in flight)
//   - otherwise R9 structure: x per-wave in LDS, A block-wide in LDS,
//     phase 3 reads MT via L2 with unroll-4 MLP
//   K1: A = Wq^T@Wk (A[j][d]), MT[d][t] = (Wv@Wk)[t][d]

#define NB 16384
#define NNBR 50
#define DIM 128
#define ROWS_W 8  // batch rows per wave

// ---------------- cross-lane add helpers -------------------------------------
template <int CTRL>
__device__ __forceinline__ float dpp_add(float x) {
  int v = __builtin_amdgcn_update_dpp(0, __builtin_bit_cast(int, x), CTRL,
                                      0xF, 0xF, true);
  return x + __builtin_bit_cast(float, v);
}

__device__ __forceinline__ float half_sum(float x) {
  x = dpp_add<0xB1>(x);   // xor 1
  x = dpp_add<0x4E>(x);   // xor 2
  x = dpp_add<0x141>(x);  // row_half_mirror
  x = dpp_add<0x140>(x);  // row_mirror
  x += __shfl_xor(x, 16, 64);
  return x;
}

// ---------------- K1: A and MT, LDS-staged (unchanged) -----------------------
__global__ __launch_bounds__(256) void precompute_weights(
    const float* __restrict__ Wq, const float* __restrict__ Wk,
    const float* __restrict__ Wv, float* __restrict__ A,
    float* __restrict__ MT) {
  __shared__ float wk[128 * 128];   // 64 KB
  __shared__ float wrow[8 * 128];   // 4 KB
  int t = threadIdx.x;
  int g = blockIdx.x;
  bool isA = g < 16;
  int r0 = (g & 15) * 8;

  const float4* wk4 = (const float4*)Wk;
  float4* wkl4 = (float4*)wk;
  #pragma unroll
  for (int i = 0; i < 16; ++i) wkl4[t + i * 256] = wk4[t + i * 256];

  if (isA) {
    #pragma unroll
    for (int i = 0; i < 4; ++i) {            // wrow[q][o] = Wq[o][r0+q]
      int idx = t + i * 256;
      int q = idx >> 7, o = idx & 127;
      wrow[q * 128 + o] = Wq[o * 128 + r0 + q];
    }
  } else {
    const float4* wv4 = (const float4*)(Wv + r0 * 128);
    float4* wr4 = (float4*)wrow;             // wrow[q][o] = Wv[r0+q][o]
    if (t < 256) wr4[t] = wv4[t];
  }
  __syncthreads();

  int d = t & 127;
  int h = (t >> 7) * 4;
  float acc[4] = {0.f, 0.f, 0.f, 0.f};
  #pragma unroll 8
  for (int o = 0; o < 128; ++o) {
    float b = wk[o * 128 + d];
    #pragma unroll
    for (int qq = 0; qq < 4; ++qq)
      acc[qq] += wrow[(h + qq) * 128 + o] * b;
  }
  if (isA) {
    #pragma unroll
    for (int qq = 0; qq < 4; ++qq) A[(r0 + h + qq) * 128 + d] = acc[qq];
  } else {
    #pragma unroll
    for (int qq = 0; qq < 4; ++qq) MT[d * 128 + r0 + h + qq] = acc[qq];
  }
}

// ---------------- K2: fused -------------------------------------------------
// 4 waves/block, 8 rows/wave -> 32 rows/block, grid = 512, 2 blocks/CU (80KB).
__global__ __launch_bounds__(256, 2) void fused_attn(
    const float* __restrict__ x, const float* __restrict__ A,
    const float* __restrict__ MT, const float* __restrict__ nbr,
    float* __restrict__ out) {
  __shared__ float ldsA[128 * 128];          // 64 KB: A (phase 1), permanent
  __shared__ float nbar_s[4 * ROWS_W][128];  // 16 KB: x rows, later nbar
  int tid = threadIdx.x;
  int wave = tid >> 6;
  int lane = tid & 63;
  int b0 = (blockIdx.x * 4 + wave) * ROWS_W;
  int c = lane & 31;

  // ---- prologue: start the HBM stream FIRST (pairs 0 and 1, 16KB/wave)
  const float4* nr0 = (const float4*)(nbr + (size_t)b0 * NNBR * DIM);
  float4 v[ROWS_W], vn[ROWS_W], vn2[ROWS_W];
  #pragma unroll
  for (int r = 0; r < ROWS_W; ++r)
    v[r] = nr0[(size_t)r * (NNBR * 32) + lane];          // pair 0
  #pragma unroll
  for (int r = 0; r < ROWS_W; ++r)
    vn[r] = nr0[(size_t)r * (NNBR * 32) + 64 + lane];    // pair 1

  // ---- phase 0a: this wave's 8 x-rows -> its own nbar_s region
  {
    const float4* xg = (const float4*)(x + (size_t)b0 * DIM);
    float4 xr[4];
    #pragma unroll
    for (int i = 0; i < 4; ++i) xr[i] = xg[i * 64 + lane];
    float4* xl = (float4*)&nbar_s[wave * ROWS_W][0];
    #pragma unroll
    for (int i = 0; i < 4; ++i) xl[i * 64 + lane] = xr[i];
  }
  // ---- phase 0b: stage A into LDS (block-wide, 16-deep MLP)
  {
    const float4* A4 = (const float4*)A;
    float4* L4 = (float4*)ldsA;
    #pragma unroll
    for (int i = 0; i < 16; ++i) L4[tid + i * 256] = A4[tid + i * 256];
  }
  __syncthreads();  // A + x visible

  // ---- phase 1: p2[r] = (x@A)[b0+r][2l..2l+1], x and A from LDS
  float2 p2[ROWS_W];
  #pragma unroll
  for (int r = 0; r < ROWS_W; ++r) p2[r] = make_float2(0.f, 0.f);

  #pragma unroll 2
  for (int j = 0; j < 128; j += 4) {
    float4 xv[ROWS_W];
    #pragma unroll
    for (int r = 0; r < ROWS_W; ++r)
      xv[r] = *(const float4*)&nbar_s[wave * ROWS_W + r][j];  // uniform bcast
    #pragma unroll
    for (int jj = 0; jj < 4; ++jj) {
      float2 a = ((const float2*)(ldsA + (j + jj) * 128))[lane];  // 2-way: free
      #pragma unroll
      for (int r = 0; r < ROWS_W; ++r) {
        float xs = (jj == 0) ? xv[r].x : (jj == 1) ? xv[r].y
                 : (jj == 2) ? xv[r].z : xv[r].w;
        p2[r].x += xs * a.x;
        p2[r].y += xs * a.y;
      }
    }
  }

  // rearrange to half-duplicated float4: lane (both halves) owns cols 4c..4c+3
  float4 p4[ROWS_W];
  #pragma unroll
  for (int r = 0; r < ROWS_W; ++r) {
    p4[r].x = __shfl(p2[r].x, 2 * c, 64);
    p4[r].y = __shfl(p2[r].y, 2 * c, 64);
    p4[r].z = __shfl(p2[r].x, 2 * c + 1, 64);
    p4[r].w = __shfl(p2[r].y, 2 * c + 1, 64);
  }

  // ---- phase 2: stream neighbors, online softmax, 2-deep prefetch
  float m[ROWS_W], l[ROWS_W];
  float4 acc[ROWS_W];
  #pragma unroll
  for (int r = 0; r < ROWS_W; ++r) {
    m[r] = -INFINITY;
    l[r] = 0.f;
    acc[r] = make_float4(0.f, 0.f, 0.f, 0.f);
  }

  for (int np = 0; np < 25; ++np) {
    int nx2 = (np + 2 < 25) ? (np + 2) : 24;     // clamp: tail re-reads
    #pragma unroll
    for (int r = 0; r < ROWS_W; ++r)
      vn2[r] = nr0[(size_t)r * (NNBR * 32) + nx2 * 64 + lane];

    #pragma unroll
    for (int r = 0; r < ROWS_W; ++r) {
      float partial = p4[r].x * v[r].x + p4[r].y * v[r].y +
                      p4[r].z * v[r].z + p4[r].w * v[r].w;
      float s = half_sum(partial);
      float so = __shfl_xor(s, 32, 64);
      float mn = fmaxf(m[r], fmaxf(s, so));
      float scale = __expf(m[r] - mn);
      float e = __expf(s - mn);
      l[r] = l[r] * scale + e;
      acc[r].x = acc[r].x * scale + e * v[r].x;
      acc[r].y = acc[r].y * scale + e * v[r].y;
      acc[r].z = acc[r].z * scale + e * v[r].z;
      acc[r].w = acc[r].w * scale + e * v[r].w;
      m[r] = mn;
      v[r] = vn[r];
      vn[r] = vn2[r];
    }
  }

  // merge half-wave accumulators; overwrite this wave's x region with nbar
  // (in-wave ordering: phase-1 x reads long done; no barrier needed)
  #pragma unroll
  for (int r = 0; r < ROWS_W; ++r) {
    l[r] += __shfl_xor(l[r], 32, 64);
    acc[r].x += __shfl_xor(acc[r].x, 32, 64);
    acc[r].y += __shfl_xor(acc[r].y, 32, 64);
    acc[r].z += __shfl_xor(acc[r].z, 32, 64);
    acc[r].w += __shfl_xor(acc[r].w, 32, 64);
  }
  if (lane < 32) {
    #pragma unroll
    for (int r = 0; r < ROWS_W; ++r) {
      float inv = 1.f / l[r];
      float4 o4 = make_float4(acc[r].x * inv, acc[r].y * inv,
                              acc[r].z * inv, acc[r].w * inv);
      *(float4*)&nbar_s[wave * ROWS_W + r][c * 4] = o4;
    }
  }

  // ---- phase 3: out[b][t] = sum_d nbar[d]*MT[d][t]; MT via L2, unroll-4 MLP
  float2 o[ROWS_W];
  #pragma unroll
  for (int r = 0; r < ROWS_W; ++r) o[r] = make_float2(0.f, 0.f);

  #pragma unroll 4
  for (int d = 0; d < 128; d += 4) {
    float4 nb[ROWS_W];
    #pragma unroll
    for (int r = 0; r < ROWS_W; ++r)
      nb[r] = *(const float4*)&nbar_s[wave * ROWS_W + r][d];  // LDS broadcast
    #pragma unroll
    for (int dd = 0; dd < 4; ++dd) {
      float2 mt = ((const float2*)(MT + (d + dd) * 128))[lane];  // 512B coalesced
      #pragma unroll
      for (int r = 0; r < ROWS_W; ++r) {
        float nv = (dd == 0) ? nb[r].x : (dd == 1) ? nb[r].y
                 : (dd == 2) ? nb[r].z : nb[r].w;
        o[r].x += nv * mt.x;
        o[r].y += nv * mt.y;
      }
    }
  }
  #pragma unroll
  for (int r = 0; r < ROWS_W; ++r)
    ((float2*)(out + (size_t)(b0 + r) * DIM))[lane] = o[r];
}

// ---------------- launcher ---------------------------------------------------
extern "C" void kernel_launch(void* const* d_in, const int* in_sizes, int n_in,
                              void* d_out, int out_size, void* d_ws,
                              size_t ws_size, hipStream_t stream) {
  const float* x   = (const float*)d_in[0];
  const float* nbr = (const float*)d_in[1];
  const float* Wq  = (const float*)d_in[2];
  const float* Wk  = (const float*)d_in[3];
  const float* Wv  = (const float*)d_in[4];
  float* out = (float*)d_out;

  char* ws = (char*)d_ws;
  float* A  = (float*)(ws);            // 64 KB
  float* MT = (float*)(ws + 65536);    // 64 KB

  precompute_weights<<<32, 256, 0, stream>>>(Wq, Wk, Wv, A, MT);
  fused_attn<<<NB / (4 * ROWS_W), 256, 0, stream>>>(x, A, MT, nbr, out);
}

// Round 11
// 89.489 us; speedup vs baseline: 3.2974x; 1.0945x over previous
//
#include <hip/hip_runtime.h>

// RelationGAT, collapsed + fused, R11:
//   - neighbor stream via __builtin_nontemporal_load (read-once data; nt flag
//     skips L2 allocation), nt store for out
//   - 3-deep prologue prefetch (pairs 0-2, 24KB/wave) fully covers the
//     phase-0/1 prologue's HBM idle; loop rotates 4 prefetch slots
//   - otherwise R10 structure: x per-wave LDS, A block-wide LDS, phase-3 MT
//     via L2 with unroll-4 MLP
//   K1: A = Wq^T@Wk (A[j][d]), MT[d][t] = (Wv@Wk)[t][d]

#define NB 16384
#define NNBR 50
#define DIM 128
#define ROWS_W 8  // batch rows per wave

typedef float f32x4 __attribute__((ext_vector_type(4)));

__device__ __forceinline__ float4 nt_load4(const float4* p) {
  f32x4 v = __builtin_nontemporal_load((const f32x4*)p);
  return make_float4(v.x, v.y, v.z, v.w);
}

// ---------------- cross-lane add helpers -------------------------------------
template <int CTRL>
__device__ __forceinline__ float dpp_add(float x) {
  int v = __builtin_amdgcn_update_dpp(0, __builtin_bit_cast(int, x), CTRL,
                                      0xF, 0xF, true);
  return x + __builtin_bit_cast(float, v);
}

__device__ __forceinline__ float half_sum(float x) {
  x = dpp_add<0xB1>(x);   // xor 1
  x = dpp_add<0x4E>(x);   // xor 2
  x = dpp_add<0x141>(x);  // row_half_mirror
  x = dpp_add<0x140>(x);  // row_mirror
  x += __shfl_xor(x, 16, 64);
  return x;
}

// ---------------- K1: A and MT, LDS-staged (unchanged) -----------------------
__global__ __launch_bounds__(256) void precompute_weights(
    const float* __restrict__ Wq, const float* __restrict__ Wk,
    const float* __restrict__ Wv, float* __restrict__ A,
    float* __restrict__ MT) {
  __shared__ float wk[128 * 128];   // 64 KB
  __shared__ float wrow[8 * 128];   // 4 KB
  int t = threadIdx.x;
  int g = blockIdx.x;
  bool isA = g < 16;
  int r0 = (g & 15) * 8;

  const float4* wk4 = (const float4*)Wk;
  float4* wkl4 = (float4*)wk;
  #pragma unroll
  for (int i = 0; i < 16; ++i) wkl4[t + i * 256] = wk4[t + i * 256];

  if (isA) {
    #pragma unroll
    for (int i = 0; i < 4; ++i) {            // wrow[q][o] = Wq[o][r0+q]
      int idx = t + i * 256;
      int q = idx >> 7, o = idx & 127;
      wrow[q * 128 + o] = Wq[o * 128 + r0 + q];
    }
  } else {
    const float4* wv4 = (const float4*)(Wv + r0 * 128);
    float4* wr4 = (float4*)wrow;             // wrow[q][o] = Wv[r0+q][o]
    if (t < 256) wr4[t] = wv4[t];
  }
  __syncthreads();

  int d = t & 127;
  int h = (t >> 7) * 4;
  float acc[4] = {0.f, 0.f, 0.f, 0.f};
  #pragma unroll 8
  for (int o = 0; o < 128; ++o) {
    float b = wk[o * 128 + d];
    #pragma unroll
    for (int qq = 0; qq < 4; ++qq)
      acc[qq] += wrow[(h + qq) * 128 + o] * b;
  }
  if (isA) {
    #pragma unroll
    for (int qq = 0; qq < 4; ++qq) A[(r0 + h + qq) * 128 + d] = acc[qq];
  } else {
    #pragma unroll
    for (int qq = 0; qq < 4; ++qq) MT[d * 128 + r0 + h + qq] = acc[qq];
  }
}

// ---------------- K2: fused -------------------------------------------------
// 4 waves/block, 8 rows/wave -> 32 rows/block, grid = 512, 2 blocks/CU (80KB).
__global__ __launch_bounds__(256, 2) void fused_attn(
    const float* __restrict__ x, const float* __restrict__ A,
    const float* __restrict__ MT, const float* __restrict__ nbr,
    float* __restrict__ out) {
  __shared__ float ldsA[128 * 128];          // 64 KB: A (phase 1), permanent
  __shared__ float nbar_s[4 * ROWS_W][128];  // 16 KB: x rows, later nbar
  int tid = threadIdx.x;
  int wave = tid >> 6;
  int lane = tid & 63;
  int b0 = (blockIdx.x * 4 + wave) * ROWS_W;
  int c = lane & 31;

  // ---- prologue: start the HBM stream FIRST (pairs 0,1,2 = 24KB/wave)
  const float4* nr0 = (const float4*)(nbr + (size_t)b0 * NNBR * DIM);
  float4 v[ROWS_W], vn[ROWS_W], vn2[ROWS_W];
  #pragma unroll
  for (int r = 0; r < ROWS_W; ++r)
    v[r] = nt_load4(nr0 + (size_t)r * (NNBR * 32) + lane);          // pair 0
  #pragma unroll
  for (int r = 0; r < ROWS_W; ++r)
    vn[r] = nt_load4(nr0 + (size_t)r * (NNBR * 32) + 64 + lane);    // pair 1
  #pragma unroll
  for (int r = 0; r < ROWS_W; ++r)
    vn2[r] = nt_load4(nr0 + (size_t)r * (NNBR * 32) + 128 + lane);  // pair 2

  // ---- phase 0a: this wave's 8 x-rows -> its own nbar_s region
  {
    const float4* xg = (const float4*)(x + (size_t)b0 * DIM);
    float4 xr[4];
    #pragma unroll
    for (int i = 0; i < 4; ++i) xr[i] = xg[i * 64 + lane];
    float4* xl = (float4*)&nbar_s[wave * ROWS_W][0];
    #pragma unroll
    for (int i = 0; i < 4; ++i) xl[i * 64 + lane] = xr[i];
  }
  // ---- phase 0b: stage A into LDS (block-wide, 16-deep MLP)
  {
    const float4* A4 = (const float4*)A;
    float4* L4 = (float4*)ldsA;
    #pragma unroll
    for (int i = 0; i < 16; ++i) L4[tid + i * 256] = A4[tid + i * 256];
  }
  __syncthreads();  // A + x visible

  // ---- phase 1: p2[r] = (x@A)[b0+r][2l..2l+1], x and A from LDS
  float2 p2[ROWS_W];
  #pragma unroll
  for (int r = 0; r < ROWS_W; ++r) p2[r] = make_float2(0.f, 0.f);

  #pragma unroll 2
  for (int j = 0; j < 128; j += 4) {
    float4 xv[ROWS_W];
    #pragma unroll
    for (int r = 0; r < ROWS_W; ++r)
      xv[r] = *(const float4*)&nbar_s[wave * ROWS_W + r][j];  // uniform bcast
    #pragma unroll
    for (int jj = 0; jj < 4; ++jj) {
      float2 a = ((const float2*)(ldsA + (j + jj) * 128))[lane];  // 2-way: free
      #pragma unroll
      for (int r = 0; r < ROWS_W; ++r) {
        float xs = (jj == 0) ? xv[r].x : (jj == 1) ? xv[r].y
                 : (jj == 2) ? xv[r].z : xv[r].w;
        p2[r].x += xs * a.x;
        p2[r].y += xs * a.y;
      }
    }
  }

  // rearrange to half-duplicated float4: lane (both halves) owns cols 4c..4c+3
  float4 p4[ROWS_W];
  #pragma unroll
  for (int r = 0; r < ROWS_W; ++r) {
    p4[r].x = __shfl(p2[r].x, 2 * c, 64);
    p4[r].y = __shfl(p2[r].y, 2 * c, 64);
    p4[r].z = __shfl(p2[r].x, 2 * c + 1, 64);
    p4[r].w = __shfl(p2[r].y, 2 * c + 1, 64);
  }

  // ---- phase 2: stream neighbors, online softmax, 3-deep rotating prefetch
  float m[ROWS_W], l[ROWS_W];
  float4 acc[ROWS_W], vn3[ROWS_W];
  #pragma unroll
  for (int r = 0; r < ROWS_W; ++r) {
    m[r] = -INFINITY;
    l[r] = 0.f;
    acc[r] = make_float4(0.f, 0.f, 0.f, 0.f);
  }

  for (int np = 0; np < 25; ++np) {
    int nx3 = (np + 3 < 25) ? (np + 3) : 24;     // clamp: tail re-reads
    #pragma unroll
    for (int r = 0; r < ROWS_W; ++r)
      vn3[r] = nt_load4(nr0 + (size_t)r * (NNBR * 32) + nx3 * 64 + lane);

    #pragma unroll
    for (int r = 0; r < ROWS_W; ++r) {
      float partial = p4[r].x * v[r].x + p4[r].y * v[r].y +
                      p4[r].z * v[r].z + p4[r].w * v[r].w;
      float s = half_sum(partial);
      float so = __shfl_xor(s, 32, 64);
      float mn = fmaxf(m[r], fmaxf(s, so));
      float scale = __expf(m[r] - mn);
      float e = __expf(s - mn);
      l[r] = l[r] * scale + e;
      acc[r].x = acc[r].x * scale + e * v[r].x;
      acc[r].y = acc[r].y * scale + e * v[r].y;
      acc[r].z = acc[r].z * scale + e * v[r].z;
      acc[r].w = acc[r].w * scale + e * v[r].w;
      m[r] = mn;
      v[r] = vn[r];
      vn[r] = vn2[r];
      vn2[r] = vn3[r];
    }
  }

  // merge half-wave accumulators; overwrite this wave's x region with nbar
  // (in-wave ordering: phase-1 x reads long done; no barrier needed)
  #pragma unroll
  for (int r = 0; r < ROWS_W; ++r) {
    l[r] += __shfl_xor(l[r], 32, 64);
    acc[r].x += __shfl_xor(acc[r].x, 32, 64);
    acc[r].y += __shfl_xor(acc[r].y, 32, 64);
    acc[r].z += __shfl_xor(acc[r].z, 32, 64);
    acc[r].w += __shfl_xor(acc[r].w, 32, 64);
  }
  if (lane < 32) {
    #pragma unroll
    for (int r = 0; r < ROWS_W; ++r) {
      float inv = 1.f / l[r];
      float4 o4 = make_float4(acc[r].x * inv, acc[r].y * inv,
                              acc[r].z * inv, acc[r].w * inv);
      *(float4*)&nbar_s[wave * ROWS_W + r][c * 4] = o4;
    }
  }

  // ---- phase 3: out[b][t] = sum_d nbar[d]*MT[d][t]; MT via L2, unroll-4 MLP
  float2 o[ROWS_W];
  #pragma unroll
  for (int r = 0; r < ROWS_W; ++r) o[r] = make_float2(0.f, 0.f);

  #pragma unroll 4
  for (int d = 0; d < 128; d += 4) {
    float4 nb[ROWS_W];
    #pragma unroll
    for (int r = 0; r < ROWS_W; ++r)
      nb[r] = *(const float4*)&nbar_s[wave * ROWS_W + r][d];  // LDS broadcast
    #pragma unroll
    for (int dd = 0; dd < 4; ++dd) {
      float2 mt = ((const float2*)(MT + (d + dd) * 128))[lane];  // 512B coalesced
      #pragma unroll
      for (int r = 0; r < ROWS_W; ++r) {
        float nv = (dd == 0) ? nb[r].x : (dd == 1) ? nb[r].y
                 : (dd == 2) ? nb[r].z : nb[r].w;
        o[r].x += nv * mt.x;
        o[r].y += nv * mt.y;
      }
    }
  }
  #pragma unroll
  for (int r = 0; r < ROWS_W; ++r) {
    float2* dst = ((float2*)(out + (size_t)(b0 + r) * DIM)) + lane;
    typedef float f32x2 __attribute__((ext_vector_type(2)));
    f32x2 val = {o[r].x, o[r].y};
    __builtin_nontemporal_store(val, (f32x2*)dst);
  }
}

// ---------------- launcher ---------------------------------------------------
extern "C" void kernel_launch(void* const* d_in, const int* in_sizes, int n_in,
                              void* d_out, int out_size, void* d_ws,
                              size_t ws_size, hipStream_t stream) {
  const float* x   = (const float*)d_in[0];
  const float* nbr = (const float*)d_in[1];
  const float* Wq  = (const float*)d_in[2];
  const float* Wk  = (const float*)d_in[3];
  const float* Wv  = (const float*)d_in[4];
  float* out = (float*)d_out;

  char* ws = (char*)d_ws;
  float* A  = (float*)(ws);            // 64 KB
  float* MT = (float*)(ws + 65536);    // 64 KB

  precompute_weights<<<32, 256, 0, stream>>>(Wq, Wk, Wv, A, MT);
  fused_attn<<<NB / (4 * ROWS_W), 256, 0, stream>>>(x, A, MT, nbr, out);
}

// Round 12
// 88.399 us; speedup vs baseline: 3.3381x; 1.0123x over previous
//
#include <hip/hip_runtime.h>

// RelationGAT, collapsed + fused, R12 = R11 + predicated tail prefetch:
//   the prefetch clamp was re-issuing the last pair 3x/row; with nt loads
//   (no L2 allocation) those re-reads went to DRAM: 2048 waves x 24 KB
//   ~= 49 MB ~= 8 us of pure waste. Loads now issued only when fresh
//   (np+3 < 25, wave-uniform scalar branch); stale slots never consumed.
//   Otherwise identical to R11.
//   K1: A = Wq^T@Wk (A[j][d]), MT[d][t] = (Wv@Wk)[t][d]

#define NB 16384
#define NNBR 50
#define DIM 128
#define ROWS_W 8  // batch rows per wave

typedef float f32x4 __attribute__((ext_vector_type(4)));

__device__ __forceinline__ float4 nt_load4(const float4* p) {
  f32x4 v = __builtin_nontemporal_load((const f32x4*)p);
  return make_float4(v.x, v.y, v.z, v.w);
}

// ---------------- cross-lane add helpers -------------------------------------
template <int CTRL>
__device__ __forceinline__ float dpp_add(float x) {
  int v = __builtin_amdgcn_update_dpp(0, __builtin_bit_cast(int, x), CTRL,
                                      0xF, 0xF, true);
  return x + __builtin_bit_cast(float, v);
}

__device__ __forceinline__ float half_sum(float x) {
  x = dpp_add<0xB1>(x);   // xor 1
  x = dpp_add<0x4E>(x);   // xor 2
  x = dpp_add<0x141>(x);  // row_half_mirror
  x = dpp_add<0x140>(x);  // row_mirror
  x += __shfl_xor(x, 16, 64);
  return x;
}

// ---------------- K1: A and MT, LDS-staged (unchanged) -----------------------
__global__ __launch_bounds__(256) void precompute_weights(
    const float* __restrict__ Wq, const float* __restrict__ Wk,
    const float* __restrict__ Wv, float* __restrict__ A,
    float* __restrict__ MT) {
  __shared__ float wk[128 * 128];   // 64 KB
  __shared__ float wrow[8 * 128];   // 4 KB
  int t = threadIdx.x;
  int g = blockIdx.x;
  bool isA = g < 16;
  int r0 = (g & 15) * 8;

  const float4* wk4 = (const float4*)Wk;
  float4* wkl4 = (float4*)wk;
  #pragma unroll
  for (int i = 0; i < 16; ++i) wkl4[t + i * 256] = wk4[t + i * 256];

  if (isA) {
    #pragma unroll
    for (int i = 0; i < 4; ++i) {            // wrow[q][o] = Wq[o][r0+q]
      int idx = t + i * 256;
      int q = idx >> 7, o = idx & 127;
      wrow[q * 128 + o] = Wq[o * 128 + r0 + q];
    }
  } else {
    const float4* wv4 = (const float4*)(Wv + r0 * 128);
    float4* wr4 = (float4*)wrow;             // wrow[q][o] = Wv[r0+q][o]
    if (t < 256) wr4[t] = wv4[t];
  }
  __syncthreads();

  int d = t & 127;
  int h = (t >> 7) * 4;
  float acc[4] = {0.f, 0.f, 0.f, 0.f};
  #pragma unroll 8
  for (int o = 0; o < 128; ++o) {
    float b = wk[o * 128 + d];
    #pragma unroll
    for (int qq = 0; qq < 4; ++qq)
      acc[qq] += wrow[(h + qq) * 128 + o] * b;
  }
  if (isA) {
    #pragma unroll
    for (int qq = 0; qq < 4; ++qq) A[(r0 + h + qq) * 128 + d] = acc[qq];
  } else {
    #pragma unroll
    for (int qq = 0; qq < 4; ++qq) MT[d * 128 + r0 + h + qq] = acc[qq];
  }
}

// ---------------- K2: fused -------------------------------------------------
// 4 waves/block, 8 rows/wave -> 32 rows/block, grid = 512, 2 blocks/CU (80KB).
__global__ __launch_bounds__(256, 2) void fused_attn(
    const float* __restrict__ x, const float* __restrict__ A,
    const float* __restrict__ MT, const float* __restrict__ nbr,
    float* __restrict__ out) {
  __shared__ float ldsA[128 * 128];          // 64 KB: A (phase 1), permanent
  __shared__ float nbar_s[4 * ROWS_W][128];  // 16 KB: x rows, later nbar
  int tid = threadIdx.x;
  int wave = tid >> 6;
  int lane = tid & 63;
  int b0 = (blockIdx.x * 4 + wave) * ROWS_W;
  int c = lane & 31;

  // ---- prologue: start the HBM stream FIRST (pairs 0,1,2 = 24KB/wave)
  const float4* nr0 = (const float4*)(nbr + (size_t)b0 * NNBR * DIM);
  float4 v[ROWS_W], vn[ROWS_W], vn2[ROWS_W];
  #pragma unroll
  for (int r = 0; r < ROWS_W; ++r)
    v[r] = nt_load4(nr0 + (size_t)r * (NNBR * 32) + lane);          // pair 0
  #pragma unroll
  for (int r = 0; r < ROWS_W; ++r)
    vn[r] = nt_load4(nr0 + (size_t)r * (NNBR * 32) + 64 + lane);    // pair 1
  #pragma unroll
  for (int r = 0; r < ROWS_W; ++r)
    vn2[r] = nt_load4(nr0 + (size_t)r * (NNBR * 32) + 128 + lane);  // pair 2

  // ---- phase 0a: this wave's 8 x-rows -> its own nbar_s region
  {
    const float4* xg = (const float4*)(x + (size_t)b0 * DIM);
    float4 xr[4];
    #pragma unroll
    for (int i = 0; i < 4; ++i) xr[i] = xg[i * 64 + lane];
    float4* xl = (float4*)&nbar_s[wave * ROWS_W][0];
    #pragma unroll
    for (int i = 0; i < 4; ++i) xl[i * 64 + lane] = xr[i];
  }
  // ---- phase 0b: stage A into LDS (block-wide, 16-deep MLP)
  {
    const float4* A4 = (const float4*)A;
    float4* L4 = (float4*)ldsA;
    #pragma unroll
    for (int i = 0; i < 16; ++i) L4[tid + i * 256] = A4[tid + i * 256];
  }
  __syncthreads();  // A + x visible

  // ---- phase 1: p2[r] = (x@A)[b0+r][2l..2l+1], x and A from LDS
  float2 p2[ROWS_W];
  #pragma unroll
  for (int r = 0; r < ROWS_W; ++r) p2[r] = make_float2(0.f, 0.f);

  #pragma unroll 2
  for (int j = 0; j < 128; j += 4) {
    float4 xv[ROWS_W];
    #pragma unroll
    for (int r = 0; r < ROWS_W; ++r)
      xv[r] = *(const float4*)&nbar_s[wave * ROWS_W + r][j];  // uniform bcast
    #pragma unroll
    for (int jj = 0; jj < 4; ++jj) {
      float2 a = ((const float2*)(ldsA + (j + jj) * 128))[lane];  // 2-way: free
      #pragma unroll
      for (int r = 0; r < ROWS_W; ++r) {
        float xs = (jj == 0) ? xv[r].x : (jj == 1) ? xv[r].y
                 : (jj == 2) ? xv[r].z : xv[r].w;
        p2[r].x += xs * a.x;
        p2[r].y += xs * a.y;
      }
    }
  }

  // rearrange to half-duplicated float4: lane (both halves) owns cols 4c..4c+3
  float4 p4[ROWS_W];
  #pragma unroll
  for (int r = 0; r < ROWS_W; ++r) {
    p4[r].x = __shfl(p2[r].x, 2 * c, 64);
    p4[r].y = __shfl(p2[r].y, 2 * c, 64);
    p4[r].z = __shfl(p2[r].x, 2 * c + 1, 64);
    p4[r].w = __shfl(p2[r].y, 2 * c + 1, 64);
  }

  // ---- phase 2: stream neighbors, online softmax, 3-deep rotating prefetch
  float m[ROWS_W], l[ROWS_W];
  float4 acc[ROWS_W], vn3[ROWS_W];
  #pragma unroll
  for (int r = 0; r < ROWS_W; ++r) {
    m[r] = -INFINITY;
    l[r] = 0.f;
    acc[r] = make_float4(0.f, 0.f, 0.f, 0.f);
  }

  for (int np = 0; np < 25; ++np) {
    // Issue prefetch ONLY while fresh pairs exist. np is wave-uniform, so
    // this is a scalar branch. Stale vn3 values rotate into slots that are
    // never consumed (last consumed v is the np=21 load).
    if (np + 3 < 25) {
      #pragma unroll
      for (int r = 0; r < ROWS_W; ++r)
        vn3[r] = nt_load4(nr0 + (size_t)r * (NNBR * 32) + (np + 3) * 64 + lane);
    }

    #pragma unroll
    for (int r = 0; r < ROWS_W; ++r) {
      float partial = p4[r].x * v[r].x + p4[r].y * v[r].y +
                      p4[r].z * v[r].z + p4[r].w * v[r].w;
      float s = half_sum(partial);
      float so = __shfl_xor(s, 32, 64);
      float mn = fmaxf(m[r], fmaxf(s, so));
      float scale = __expf(m[r] - mn);
      float e = __expf(s - mn);
      l[r] = l[r] * scale + e;
      acc[r].x = acc[r].x * scale + e * v[r].x;
      acc[r].y = acc[r].y * scale + e * v[r].y;
      acc[r].z = acc[r].z * scale + e * v[r].z;
      acc[r].w = acc[r].w * scale + e * v[r].w;
      m[r] = mn;
      v[r] = vn[r];
      vn[r] = vn2[r];
      vn2[r] = vn3[r];
    }
  }

  // merge half-wave accumulators; overwrite this wave's x region with nbar
  // (in-wave ordering: phase-1 x reads long done; no barrier needed)
  #pragma unroll
  for (int r = 0; r < ROWS_W; ++r) {
    l[r] += __shfl_xor(l[r], 32, 64);
    acc[r].x += __shfl_xor(acc[r].x, 32, 64);
    acc[r].y += __shfl_xor(acc[r].y, 32, 64);
    acc[r].z += __shfl_xor(acc[r].z, 32, 64);
    acc[r].w += __shfl_xor(acc[r].w, 32, 64);
  }
  if (lane < 32) {
    #pragma unroll
    for (int r = 0; r < ROWS_W; ++r) {
      float inv = 1.f / l[r];
      float4 o4 = make_float4(acc[r].x * inv, acc[r].y * inv,
                              acc[r].z * inv, acc[r].w * inv);
      *(float4*)&nbar_s[wave * ROWS_W + r][c * 4] = o4;
    }
  }

  // ---- phase 3: out[b][t] = sum_d nbar[d]*MT[d][t]; MT via L2, unroll-4 MLP
  float2 o[ROWS_W];
  #pragma unroll
  for (int r = 0; r < ROWS_W; ++r) o[r] = make_float2(0.f, 0.f);

  #pragma unroll 4
  for (int d = 0; d < 128; d += 4) {
    float4 nb[ROWS_W];
    #pragma unroll
    for (int r = 0; r < ROWS_W; ++r)
      nb[r] = *(const float4*)&nbar_s[wave * ROWS_W + r][d];  // LDS broadcast
    #pragma unroll
    for (int dd = 0; dd < 4; ++dd) {
      float2 mt = ((const float2*)(MT + (d + dd) * 128))[lane];  // 512B coalesced
      #pragma unroll
      for (int r = 0; r < ROWS_W; ++r) {
        float nv = (dd == 0) ? nb[r].x : (dd == 1) ? nb[r].y
                 : (dd == 2) ? nb[r].z : nb[r].w;
        o[r].x += nv * mt.x;
        o[r].y += nv * mt.y;
      }
    }
  }
  #pragma unroll
  for (int r = 0; r < ROWS_W; ++r) {
    float2* dst = ((float2*)(out + (size_t)(b0 + r) * DIM)) + lane;
    typedef float f32x2 __attribute__((ext_vector_type(2)));
    f32x2 val = {o[r].x, o[r].y};
    __builtin_nontemporal_store(val, (f32x2*)dst);
  }
}

// ---------------- launcher ---------------------------------------------------
extern "C" void kernel_launch(void* const* d_in, const int* in_sizes, int n_in,
                              void* d_out, int out_size, void* d_ws,
                              size_t ws_size, hipStream_t stream) {
  const float* x   = (const float*)d_in[0];
  const float* nbr = (const float*)d_in[1];
  const float* Wq  = (const float*)d_in[2];
  const float* Wk  = (const float*)d_in[3];
  const float* Wv  = (const float*)d_in[4];
  float* out = (float*)d_out;

  char* ws = (char*)d_ws;
  float* A  = (float*)(ws);            // 64 KB
  float* MT = (float*)(ws + 65536);    // 64 KB

  precompute_weights<<<32, 256, 0, stream>>>(Wq, Wk, Wv, A, MT);
  fused_attn<<<NB / (4 * ROWS_W), 256, 0, stream>>>(x, A, MT, nbr, out);
}